// Round 1
// baseline (3231.129 us; speedup 1.0000x reference)
//
#include <hip/hip_runtime.h>

#define NN 50000
#define EE 800000
#define GG 64
#define FF 128
#define NBES 8
#define RMAXF 5.0f
#define PI_F 3.14159265358979323846f

// spherical harmonic constants
#define S3  1.7320508075688772f
#define S5  2.23606797749979f
#define S15 3.872983346207417f
#define C1c 2.091650066335189f   // sqrt(35/8)
#define C2c 10.246950765959598f  // sqrt(105)
#define C3c 1.62018517460196f    // sqrt(21/8)
#define C4c 1.3228756555322954f  // sqrt(7)/2
#define C5c 5.123475382979799f   // sqrt(105)/2
#define CCB 0.6324555320336759f  // sqrt(2/5)

__device__ __forceinline__ float shc_s(float x, float y, float z, const float* __restrict__ w) {
    float x2 = x * x, y2 = y * y, z2 = z * z;
    return w[0]
        + w[1] * (S3 * x) + w[2] * (S3 * y) + w[3] * (S3 * z)
        + w[4] * (S15 * x * y) + w[5] * (S15 * y * z) + w[6] * (0.5f * S5 * (3.f * z2 - 1.f))
        + w[7] * (S15 * x * z) + w[8] * (0.5f * S15 * (x2 - y2))
        + w[9] * (C1c * y * (3.f * x2 - y2)) + w[10] * (C2c * x * y * z)
        + w[11] * (C3c * y * (5.f * z2 - 1.f)) + w[12] * (C4c * z * (5.f * z2 - 3.f))
        + w[13] * (C3c * x * (5.f * z2 - 1.f)) + w[14] * (C5c * z * (x2 - y2))
        + w[15] * (C1c * x * (x2 - 3.f * y2));
}

__device__ __forceinline__ void shc_grad(float x, float y, float z, const float* __restrict__ w,
                                         float& gx, float& gy, float& gz) {
    float x2 = x * x, y2 = y * y, z2 = z * z;
    gx = w[1] * S3 + w[4] * (S15 * y) + w[7] * (S15 * z) + w[8] * (S15 * x)
       + w[9] * (6.f * C1c * x * y) + w[10] * (C2c * y * z) + w[13] * (C3c * (5.f * z2 - 1.f))
       + w[14] * (2.f * C5c * x * z) + w[15] * (3.f * C1c * (x2 - y2));
    gy = w[2] * S3 + w[4] * (S15 * x) + w[5] * (S15 * z) - w[8] * (S15 * y)
       + w[9] * (3.f * C1c * (x2 - y2)) + w[10] * (C2c * x * z) + w[11] * (C3c * (5.f * z2 - 1.f))
       - w[14] * (2.f * C5c * y * z) - w[15] * (6.f * C1c * x * y);
    gz = w[3] * S3 + w[5] * (S15 * y) + w[6] * (3.f * S5 * z) + w[7] * (S15 * x)
       + w[10] * (C2c * x * y) + w[11] * (10.f * C3c * y * z) + w[12] * (C4c * (15.f * z2 - 3.f))
       + w[13] * (10.f * C3c * x * z) + w[14] * (C5c * (x2 - y2));
}

// eb[k] (and optionally d eb[k]/dr) for k=1..8; caller guarantees r < RMAXF
template <bool BWD>
__device__ __forceinline__ void radial(float r, float inv_r, float* eb, float* debdr) {
    float u = r * (1.0f / RMAXF);
    float th = PI_F * u;
    float s1 = sinf(th), c1 = cosf(th);
    float u2 = u * u, u3 = u2 * u, u5 = u2 * u3, u6 = u3 * u3, u7 = u6 * u, u8 = u6 * u2;
    float env = 1.f - 28.f * u6 + 48.f * u7 - 21.f * u8;
    float denv = (-168.f * u5 + 336.f * u6 - 168.f * u7) * (1.0f / RMAXF);
    float sk = s1, skm = 0.f, ck = c1, ckm = 1.f;
    float tc = 2.f * c1;
#pragma unroll
    for (int k = 1; k <= NBES; k++) {
        float b = CCB * sk * inv_r;
        eb[k - 1] = b * env;
        if (BWD) {
            debdr[k - 1] = CCB * (((float)k * PI_F * (1.0f / RMAXF)) * ck * inv_r
                                  - sk * inv_r * inv_r) * env
                           + b * denv;
        }
        float sn = tc * sk - skm; skm = sk; sk = sn;
        float cn = tc * ck - ckm; ckm = ck; ck = cn;
    }
}

// -------------------- forward --------------------

__global__ __launch_bounds__(256) void e0_kernel(const float* __restrict__ attrs,
                                                 const float* __restrict__ ae,
                                                 const int* __restrict__ batch,
                                                 float* __restrict__ energy) {
    int n = blockIdx.x * 256 + threadIdx.x;
    if (n >= NN) return;
    float s = 0.f;
#pragma unroll
    for (int a = 0; a < 10; a++) s += attrs[n * 10 + a] * ae[a];
    atomicAdd(&energy[batch[n]], s);
}

// one wave (64 lanes) per edge; 2 features per lane
template <bool USE_H>
__global__ __launch_bounds__(256) void edge_fwd(const float* __restrict__ pos,
                                                const float* __restrict__ shifts,
                                                const int* __restrict__ ei,
                                                const float* __restrict__ h_in,
                                                const float* __restrict__ attrs,
                                                const float* __restrict__ W_emb,
                                                const float* __restrict__ Wr,
                                                const float* __restrict__ wsh,
                                                float* __restrict__ agg) {
    int e = (blockIdx.x * 256 + threadIdx.x) >> 6;
    int lane = threadIdx.x & 63;
    int snd = ei[e];
    int rcv = ei[EE + e];
    float vx = pos[rcv * 3 + 0] - pos[snd * 3 + 0] + shifts[e * 3 + 0];
    float vy = pos[rcv * 3 + 1] - pos[snd * 3 + 1] + shifts[e * 3 + 1];
    float vz = pos[rcv * 3 + 2] - pos[snd * 3 + 2] + shifts[e * 3 + 2];
    float r2 = vx * vx + vy * vy + vz * vz + 1e-12f;
    float r = sqrtf(r2);
    if (r >= RMAXF) return;  // message is exactly zero
    float inv_r = 1.0f / r;
    float x = vx * inv_r, y = vy * inv_r, z = vz * inv_r;
    float s = shc_s(x, y, z, wsh);
    float eb[NBES];
    radial<false>(r, inv_r, eb, nullptr);
#pragma unroll
    for (int t = 0; t < 2; t++) {
        int f = lane + (t << 6);
        float R = 0.f;
#pragma unroll
        for (int k = 0; k < NBES; k++) R += eb[k] * Wr[k * FF + f];
        float h;
        if (USE_H) {
            h = h_in[snd * FF + f];
        } else {
            h = 0.f;
#pragma unroll
            for (int a = 0; a < 10; a++) h += attrs[snd * 10 + a] * W_emb[a * FF + f];
        }
        atomicAdd(&agg[rcv * FF + f], h * R * s);
    }
}

// 2 nodes per 256-thread block; h = agg@W_out + attrs@W_skip; node energy atomic
__global__ __launch_bounds__(256) void node_update(const float* __restrict__ agg,
                                                   const float* __restrict__ attrs,
                                                   const float* __restrict__ Wout,
                                                   const float* __restrict__ Wskip,
                                                   const float* __restrict__ wread,
                                                   const int* __restrict__ batch,
                                                   float* __restrict__ h_out,  // nullable
                                                   float* __restrict__ energy) {
    __shared__ float sa[2][FF];
    __shared__ float red[4];
    int sub = threadIdx.x >> 7;
    int f = threadIdx.x & 127;
    int n = blockIdx.x * 2 + sub;
    sa[sub][f] = agg[n * FF + f];
    __syncthreads();
    float acc = 0.f;
#pragma unroll 8
    for (int k = 0; k < FF; k++) acc += sa[sub][k] * Wout[k * FF + f];
#pragma unroll
    for (int a = 0; a < 10; a++) acc += attrs[n * 10 + a] * Wskip[a * FF + f];
    if (h_out) h_out[n * FF + f] = acc;
    float p = acc * wread[f];
#pragma unroll
    for (int o = 32; o > 0; o >>= 1) p += __shfl_xor(p, o);
    int wid = threadIdx.x >> 6;
    if ((threadIdx.x & 63) == 0) red[wid] = p;
    __syncthreads();
    if (f == 0) atomicAdd(&energy[batch[n]], red[2 * sub] + red[2 * sub + 1]);
}

// -------------------- backward helpers --------------------

__global__ __launch_bounds__(128) void a1_kernel(const float* __restrict__ Wout1,
                                                 const float* __restrict__ wread1,
                                                 float* __restrict__ a1) {
    int f = threadIdx.x;
    float s = 0.f;
    for (int k = 0; k < FF; k++) s += Wout1[f * FF + k] * wread1[k];
    a1[f] = s;
}

__global__ __launch_bounds__(256) void transpose_kernel(const float* __restrict__ Wout0,
                                                        float* __restrict__ WoT) {
    int idx = blockIdx.x * 256 + threadIdx.x;  // 0..16383
    int f = idx & 127;
    int k = idx >> 7;
    WoT[k * FF + f] = Wout0[f * FF + k];
}

__global__ __launch_bounds__(256) void gh_init_kernel(const float* __restrict__ wread0,
                                                      float* __restrict__ gh) {
    int idx = blockIdx.x * 256 + threadIdx.x;
    gh[idx] = wread0[idx & 127];
}

// b0[n][f] = sum_k g1[n][k] * W_out0[f][k]  (WoT = W_out0 transposed)
__global__ __launch_bounds__(256) void node_b0(const float* __restrict__ gh,
                                               const float* __restrict__ WoT,
                                               float* __restrict__ b0out) {
    __shared__ float sa[2][FF];
    int sub = threadIdx.x >> 7;
    int f = threadIdx.x & 127;
    int n = blockIdx.x * 2 + sub;
    sa[sub][f] = gh[n * FF + f];
    __syncthreads();
    float acc = 0.f;
#pragma unroll 8
    for (int k = 0; k < FF; k++) acc += sa[sub][k] * WoT[k * FF + f];
    b0out[n * FF + f] = acc;
}

// one wave per edge. LAYER1: dm = a1 (uniform F-vec), h = h1, emits gh atomic.
// layer0: dm = b0[rcv], h = attrs@W_emb on the fly, no gh.
template <bool LAYER1>
__global__ __launch_bounds__(256) void edge_bwd(const float* __restrict__ pos,
                                                const float* __restrict__ shifts,
                                                const int* __restrict__ ei,
                                                const float* __restrict__ h_in,
                                                const float* __restrict__ attrs,
                                                const float* __restrict__ W_emb,
                                                const float* __restrict__ Wr,
                                                const float* __restrict__ wsh,
                                                const float* __restrict__ a1,
                                                const float* __restrict__ b0,
                                                float* __restrict__ gh,
                                                float* __restrict__ forces) {
    int e = (blockIdx.x * 256 + threadIdx.x) >> 6;
    int lane = threadIdx.x & 63;
    int snd = ei[e];
    int rcv = ei[EE + e];
    float vx = pos[rcv * 3 + 0] - pos[snd * 3 + 0] + shifts[e * 3 + 0];
    float vy = pos[rcv * 3 + 1] - pos[snd * 3 + 1] + shifts[e * 3 + 1];
    float vz = pos[rcv * 3 + 2] - pos[snd * 3 + 2] + shifts[e * 3 + 2];
    float r2 = vx * vx + vy * vy + vz * vz + 1e-12f;
    float r = sqrtf(r2);
    if (r >= RMAXF) return;  // all grads vanish (eb == 0 and d eb == 0 at cutoff)
    float inv_r = 1.0f / r;
    float x = vx * inv_r, y = vy * inv_r, z = vz * inv_r;
    float s = shc_s(x, y, z, wsh);
    float eb[NBES], debdr[NBES];
    radial<true>(r, inv_r, eb, debdr);

    float dsp = 0.f;
    float t[NBES];
#pragma unroll
    for (int k = 0; k < NBES; k++) t[k] = 0.f;

#pragma unroll
    for (int tt = 0; tt < 2; tt++) {
        int f = lane + (tt << 6);
        float wr[NBES];
#pragma unroll
        for (int k = 0; k < NBES; k++) wr[k] = Wr[k * FF + f];
        float Rf = 0.f;
#pragma unroll
        for (int k = 0; k < NBES; k++) Rf += eb[k] * wr[k];
        float dmf, hf;
        if (LAYER1) {
            dmf = a1[f];
            hf = h_in[snd * FF + f];
        } else {
            dmf = b0[rcv * FF + f];
            hf = 0.f;
#pragma unroll
            for (int a = 0; a < 10; a++) hf += attrs[snd * 10 + a] * W_emb[a * FF + f];
        }
        float dh = dmf * hf;
        dsp += dh * Rf;
#pragma unroll
        for (int k = 0; k < NBES; k++) t[k] += dh * wr[k];
        if (LAYER1) atomicAdd(&gh[snd * FF + f], dmf * Rf * s);
    }

    // wave-wide butterfly reduce of dsp and t[0..7]
#pragma unroll
    for (int o = 32; o > 0; o >>= 1) {
        dsp += __shfl_xor(dsp, o);
#pragma unroll
        for (int k = 0; k < NBES; k++) t[k] += __shfl_xor(t[k], o);
    }

    if (lane == 0) {
        float gr = 0.f;
#pragma unroll
        for (int k = 0; k < NBES; k++) gr += t[k] * debdr[k];
        gr *= s;  // deb[k] = s * t[k]
        float gux, guy, guz;
        shc_grad(x, y, z, wsh, gux, guy, guz);
        gux *= dsp; guy *= dsp; guz *= dsp;
        float dgu = gux * x + guy * y + guz * z;
        float gvx = gr * x + inv_r * (gux - dgu * x);
        float gvy = gr * y + inv_r * (guy - dgu * y);
        float gvz = gr * z + inv_r * (guz - dgu * z);
        // forces = -dE/dpos; dE/dpos[rcv] += gv, dE/dpos[snd] -= gv
        atomicAdd(&forces[snd * 3 + 0], gvx);
        atomicAdd(&forces[snd * 3 + 1], gvy);
        atomicAdd(&forces[snd * 3 + 2], gvz);
        atomicAdd(&forces[rcv * 3 + 0], -gvx);
        atomicAdd(&forces[rcv * 3 + 1], -gvy);
        atomicAdd(&forces[rcv * 3 + 2], -gvz);
    }
}

// -------------------- launch --------------------

extern "C" void kernel_launch(void* const* d_in, const int* in_sizes, int n_in,
                              void* d_out, int out_size, void* d_ws, size_t ws_size,
                              hipStream_t stream) {
    const float* pos    = (const float*)d_in[0];
    const float* attrs  = (const float*)d_in[1];
    const float* shifts = (const float*)d_in[2];
    const int*   ei     = (const int*)d_in[3];
    const int*   batch  = (const int*)d_in[4];
    // d_in[5] = num_graphs (unused, fixed GG)
    const float* W_emb  = (const float*)d_in[6];
    const float* ae     = (const float*)d_in[7];
    const float* W_r    = (const float*)d_in[8];   // (2,8,F)
    const float* w_sh   = (const float*)d_in[9];   // (2,16)
    const float* W_out  = (const float*)d_in[10];  // (2,F,F)
    const float* W_skip = (const float*)d_in[11];  // (2,10,F)
    const float* w_read = (const float*)d_in[12];  // (2,F)

    float* energy = (float*)d_out;      // [0,64)
    float* forces = energy + GG;        // [64, 64+3N)

    float* ws  = (float*)d_ws;
    float* h1  = ws;                    // N*F
    float* agg = h1 + (size_t)NN * FF;  // N*F (later reused as b0)
    float* gh  = agg + (size_t)NN * FF; // N*F
    float* a1  = gh + (size_t)NN * FF;  // F
    float* WoT = a1 + FF;               // F*F

    const int edgeBlocks = EE / 4;       // 4 waves (edges) per 256-thread block
    const int nodeBlocks = NN / 2;

    hipMemsetAsync(d_out, 0, (size_t)out_size * sizeof(float), stream);
    hipMemsetAsync(agg, 0, (size_t)NN * FF * sizeof(float), stream);

    e0_kernel<<<(NN + 255) / 256, 256, 0, stream>>>(attrs, ae, batch, energy);

    // layer 0 forward
    edge_fwd<false><<<edgeBlocks, 256, 0, stream>>>(pos, shifts, ei, nullptr, attrs, W_emb,
                                                    W_r, w_sh, agg);
    node_update<<<nodeBlocks, 256, 0, stream>>>(agg, attrs, W_out, W_skip, w_read, batch,
                                                h1, energy);

    // layer 1 forward
    hipMemsetAsync(agg, 0, (size_t)NN * FF * sizeof(float), stream);
    edge_fwd<true><<<edgeBlocks, 256, 0, stream>>>(pos, shifts, ei, h1, attrs, W_emb,
                                                   W_r + NBES * FF, w_sh + 16, agg);
    node_update<<<nodeBlocks, 256, 0, stream>>>(agg, attrs, W_out + FF * FF, W_skip + 10 * FF,
                                                w_read + FF, batch, nullptr, energy);

    // backward prep
    a1_kernel<<<1, 128, 0, stream>>>(W_out + FF * FF, w_read + FF, a1);
    transpose_kernel<<<FF * FF / 256, 256, 0, stream>>>(W_out, WoT);
    gh_init_kernel<<<NN * FF / 256, 256, 0, stream>>>(w_read, gh);

    // layer 1 backward (accumulates gh1 and forces)
    edge_bwd<true><<<edgeBlocks, 256, 0, stream>>>(pos, shifts, ei, h1, attrs, W_emb,
                                                   W_r + NBES * FF, w_sh + 16, a1, nullptr,
                                                   gh, forces);
    // b0 = W_out0 . g1 (into agg buffer)
    node_b0<<<nodeBlocks, 256, 0, stream>>>(gh, WoT, agg);

    // layer 0 backward (forces only)
    edge_bwd<false><<<edgeBlocks, 256, 0, stream>>>(pos, shifts, ei, nullptr, attrs, W_emb,
                                                    W_r, w_sh, nullptr, agg, nullptr, forces);
}

// Round 2
// 2918.423 us; speedup vs baseline: 1.1071x; 1.1071x over previous
//
#include <hip/hip_runtime.h>

#define NN 50000
#define EE 800000
#define GG 64
#define FF 128
#define NBES 8
#define RMAXF 5.0f
#define PI_F 3.14159265358979323846f

// spherical harmonic constants
#define S3  1.7320508075688772f
#define S5  2.23606797749979f
#define S15 3.872983346207417f
#define C1c 2.091650066335189f   // sqrt(35/8)
#define C2c 10.246950765959598f  // sqrt(105)
#define C3c 1.62018517460196f    // sqrt(21/8)
#define C4c 1.3228756555322954f  // sqrt(7)/2
#define C5c 5.123475382979799f   // sqrt(105)/2
#define CCB 0.6324555320336759f  // sqrt(2/5)

__device__ __forceinline__ float shc_s(float x, float y, float z, const float* __restrict__ w) {
    float x2 = x * x, y2 = y * y, z2 = z * z;
    return w[0]
        + w[1] * (S3 * x) + w[2] * (S3 * y) + w[3] * (S3 * z)
        + w[4] * (S15 * x * y) + w[5] * (S15 * y * z) + w[6] * (0.5f * S5 * (3.f * z2 - 1.f))
        + w[7] * (S15 * x * z) + w[8] * (0.5f * S15 * (x2 - y2))
        + w[9] * (C1c * y * (3.f * x2 - y2)) + w[10] * (C2c * x * y * z)
        + w[11] * (C3c * y * (5.f * z2 - 1.f)) + w[12] * (C4c * z * (5.f * z2 - 3.f))
        + w[13] * (C3c * x * (5.f * z2 - 1.f)) + w[14] * (C5c * z * (x2 - y2))
        + w[15] * (C1c * x * (x2 - 3.f * y2));
}

__device__ __forceinline__ void shc_grad(float x, float y, float z, const float* __restrict__ w,
                                         float& gx, float& gy, float& gz) {
    float x2 = x * x, y2 = y * y, z2 = z * z;
    gx = w[1] * S3 + w[4] * (S15 * y) + w[7] * (S15 * z) + w[8] * (S15 * x)
       + w[9] * (6.f * C1c * x * y) + w[10] * (C2c * y * z) + w[13] * (C3c * (5.f * z2 - 1.f))
       + w[14] * (2.f * C5c * x * z) + w[15] * (3.f * C1c * (x2 - y2));
    gy = w[2] * S3 + w[4] * (S15 * x) + w[5] * (S15 * z) - w[8] * (S15 * y)
       + w[9] * (3.f * C1c * (x2 - y2)) + w[10] * (C2c * x * z) + w[11] * (C3c * (5.f * z2 - 1.f))
       - w[14] * (2.f * C5c * y * z) - w[15] * (6.f * C1c * x * y);
    gz = w[3] * S3 + w[5] * (S15 * y) + w[6] * (3.f * S5 * z) + w[7] * (S15 * x)
       + w[10] * (C2c * x * y) + w[11] * (10.f * C3c * y * z) + w[12] * (C4c * (15.f * z2 - 3.f))
       + w[13] * (10.f * C3c * x * z) + w[14] * (C5c * (x2 - y2));
}

// geo SoA layout (arrays of EE floats):
//   [0..7]  eb[k]
//   [8]     s0
//   [9]     s1
//   [10..17] debdr[k]
//   [18] dsp0  [19] drp0  [20] dsp1  [21] drp1
#define G_EB(k)  ((size_t)(k) * EE)
#define G_S0     ((size_t)8 * EE)
#define G_S1     ((size_t)9 * EE)
#define G_DB(k)  ((size_t)(10 + (k)) * EE)
#define G_DSP0   ((size_t)18 * EE)
#define G_DRP0   ((size_t)19 * EE)
#define G_DSP1   ((size_t)20 * EE)
#define G_DRP1   ((size_t)21 * EE)

// -------------------- geometry (thread-per-edge) --------------------

__global__ __launch_bounds__(256) void edge_geom(const float* __restrict__ pos,
                                                 const float* __restrict__ shifts,
                                                 const int* __restrict__ ei,
                                                 const float* __restrict__ wsh,  // (2,16)
                                                 float* __restrict__ geo) {
    int e = blockIdx.x * 256 + threadIdx.x;
    if (e >= EE) return;
    int snd = ei[e];
    int rcv = ei[EE + e];
    float vx = pos[rcv * 3 + 0] - pos[snd * 3 + 0] + shifts[e * 3 + 0];
    float vy = pos[rcv * 3 + 1] - pos[snd * 3 + 1] + shifts[e * 3 + 1];
    float vz = pos[rcv * 3 + 2] - pos[snd * 3 + 2] + shifts[e * 3 + 2];
    float r2 = vx * vx + vy * vy + vz * vz + 1e-12f;
    float r = sqrtf(r2);
    float inv_r = 1.0f / r;
    float x = vx * inv_r, y = vy * inv_r, z = vz * inv_r;
    float valid = (r < RMAXF) ? 1.f : 0.f;

    geo[G_S0 + e] = shc_s(x, y, z, wsh);
    geo[G_S1 + e] = shc_s(x, y, z, wsh + 16);

    float u = r * (1.0f / RMAXF);
    float th = PI_F * u;
    float s1 = sinf(th), c1 = cosf(th);
    float u2 = u * u, u3 = u2 * u, u5 = u2 * u3, u6 = u3 * u3, u7 = u6 * u, u8 = u6 * u2;
    float env = (1.f - 28.f * u6 + 48.f * u7 - 21.f * u8) * valid;
    float denv = (-168.f * u5 + 336.f * u6 - 168.f * u7) * (1.0f / RMAXF) * valid;
    float sk = s1, skm = 0.f, ck = c1, ckm = 1.f;
    float tc = 2.f * c1;
#pragma unroll
    for (int k = 1; k <= NBES; k++) {
        float b = CCB * sk * inv_r;
        geo[G_EB(k - 1) + e] = b * env;
        geo[G_DB(k - 1) + e] = CCB * (((float)k * PI_F * (1.0f / RMAXF)) * ck * inv_r
                                      - sk * inv_r * inv_r) * env
                               + b * denv;
        float sn = tc * sk - skm; skm = sk; sk = sn;
        float cn = tc * ck - ckm; ckm = ck; ck = cn;
    }
}

// -------------------- node prep --------------------

__global__ __launch_bounds__(256) void e0_kernel(const float* __restrict__ attrs,
                                                 const float* __restrict__ ae,
                                                 const int* __restrict__ batch,
                                                 float* __restrict__ energy) {
    int n = blockIdx.x * 256 + threadIdx.x;
    if (n >= NN) return;
    float s = 0.f;
#pragma unroll
    for (int a = 0; a < 10; a++) s += attrs[n * 10 + a] * ae[a];
    atomicAdd(&energy[batch[n]], s);
}

// h0 = attrs @ W_emb, 2 nodes per block
__global__ __launch_bounds__(256) void h0_kernel(const float* __restrict__ attrs,
                                                 const float* __restrict__ W_emb,
                                                 float* __restrict__ h0) {
    int sub = threadIdx.x >> 7;
    int f = threadIdx.x & 127;
    int n = blockIdx.x * 2 + sub;
    float acc = 0.f;
#pragma unroll
    for (int a = 0; a < 10; a++) acc += attrs[n * 10 + a] * W_emb[a * FF + f];
    h0[n * FF + f] = acc;
}

// -------------------- edge feature kernels (wave-per-edge, grid-stride) --------------------

__global__ __launch_bounds__(256) void edge_fwd_feat(const float* __restrict__ geo,
                                                     const float* __restrict__ geo_s,
                                                     const int* __restrict__ ei,
                                                     const float* __restrict__ h_src,
                                                     const float* __restrict__ Wr,
                                                     float* __restrict__ agg) {
    int wave = (blockIdx.x * 256 + threadIdx.x) >> 6;
    int lane = threadIdx.x & 63;
    int nwaves = gridDim.x * 4;
    int f0 = lane, f1 = lane + 64;
    float wr0[NBES], wr1[NBES];
#pragma unroll
    for (int k = 0; k < NBES; k++) { wr0[k] = Wr[k * FF + f0]; wr1[k] = Wr[k * FF + f1]; }

    for (int e = wave; e < EE; e += nwaves) {
        int snd = ei[e];
        int rcv = ei[EE + e];
        float s = geo_s[e];
        float R0 = 0.f, R1 = 0.f;
#pragma unroll
        for (int k = 0; k < NBES; k++) {
            float eb = geo[G_EB(k) + e];
            R0 += eb * wr0[k];
            R1 += eb * wr1[k];
        }
        float h0 = h_src[snd * FF + f0];
        float h1 = h_src[snd * FF + f1];
        atomicAdd(&agg[rcv * FF + f0], h0 * R0 * s);
        atomicAdd(&agg[rcv * FF + f1], h1 * R1 * s);
    }
}

// backward feature pass: reduce dsp = sum_f dm*h*R, drp = sum_f dm*h*Rd; layer1 also emits gh.
template <bool LAYER1>
__global__ __launch_bounds__(256) void edge_bwd_feat(const float* __restrict__ geo,
                                                     const float* __restrict__ geo_s,
                                                     const int* __restrict__ ei,
                                                     const float* __restrict__ h_src,
                                                     const float* __restrict__ Wr,
                                                     const float* __restrict__ a1,
                                                     const float* __restrict__ b0,
                                                     float* __restrict__ gh,
                                                     float* __restrict__ dsp_out,
                                                     float* __restrict__ drp_out) {
    int wave = (blockIdx.x * 256 + threadIdx.x) >> 6;
    int lane = threadIdx.x & 63;
    int nwaves = gridDim.x * 4;
    int f0 = lane, f1 = lane + 64;
    float wr0[NBES], wr1[NBES];
#pragma unroll
    for (int k = 0; k < NBES; k++) { wr0[k] = Wr[k * FF + f0]; wr1[k] = Wr[k * FF + f1]; }
    float dm0u = 0.f, dm1u = 0.f;
    if (LAYER1) { dm0u = a1[f0]; dm1u = a1[f1]; }

    for (int e = wave; e < EE; e += nwaves) {
        int snd = ei[e];
        int rcv = ei[EE + e];
        float R0 = 0.f, R1 = 0.f, Rd0 = 0.f, Rd1 = 0.f;
#pragma unroll
        for (int k = 0; k < NBES; k++) {
            float eb = geo[G_EB(k) + e];
            float db = geo[G_DB(k) + e];
            R0 += eb * wr0[k];
            R1 += eb * wr1[k];
            Rd0 += db * wr0[k];
            Rd1 += db * wr1[k];
        }
        float dm0, dm1;
        if (LAYER1) { dm0 = dm0u; dm1 = dm1u; }
        else        { dm0 = b0[rcv * FF + f0]; dm1 = b0[rcv * FF + f1]; }
        float dh0 = dm0 * h_src[snd * FF + f0];
        float dh1 = dm1 * h_src[snd * FF + f1];
        float dsp = dh0 * R0 + dh1 * R1;
        float drp = dh0 * Rd0 + dh1 * Rd1;
#pragma unroll
        for (int o = 32; o > 0; o >>= 1) {
            dsp += __shfl_xor(dsp, o);
            drp += __shfl_xor(drp, o);
        }
        if (LAYER1) {
            float s = geo_s[e];
            atomicAdd(&gh[snd * FF + f0], dm0 * R0 * s);
            atomicAdd(&gh[snd * FF + f1], dm1 * R1 * s);
        }
        if (lane == 0) { dsp_out[e] = dsp; drp_out[e] = drp; }
    }
}

// -------------------- force finalize (thread-per-edge, both layers) --------------------

__global__ __launch_bounds__(256) void force_kernel(const float* __restrict__ pos,
                                                    const float* __restrict__ shifts,
                                                    const int* __restrict__ ei,
                                                    const float* __restrict__ wsh,
                                                    const float* __restrict__ geo,
                                                    float* __restrict__ forces) {
    int e = blockIdx.x * 256 + threadIdx.x;
    if (e >= EE) return;
    int snd = ei[e];
    int rcv = ei[EE + e];
    float vx = pos[rcv * 3 + 0] - pos[snd * 3 + 0] + shifts[e * 3 + 0];
    float vy = pos[rcv * 3 + 1] - pos[snd * 3 + 1] + shifts[e * 3 + 1];
    float vz = pos[rcv * 3 + 2] - pos[snd * 3 + 2] + shifts[e * 3 + 2];
    float r2 = vx * vx + vy * vy + vz * vz + 1e-12f;
    float r = sqrtf(r2);
    float inv_r = 1.0f / r;
    float x = vx * inv_r, y = vy * inv_r, z = vz * inv_r;

    float dsp0 = geo[G_DSP0 + e], drp0 = geo[G_DRP0 + e];
    float dsp1 = geo[G_DSP1 + e], drp1 = geo[G_DRP1 + e];
    float s0 = geo[G_S0 + e], s1v = geo[G_S1 + e];

    float g0x, g0y, g0z, g1x, g1y, g1z;
    shc_grad(x, y, z, wsh, g0x, g0y, g0z);
    shc_grad(x, y, z, wsh + 16, g1x, g1y, g1z);
    float gux = dsp0 * g0x + dsp1 * g1x;
    float guy = dsp0 * g0y + dsp1 * g1y;
    float guz = dsp0 * g0z + dsp1 * g1z;
    float gr = s0 * drp0 + s1v * drp1;
    float dgu = gux * x + guy * y + guz * z;
    float gvx = gr * x + inv_r * (gux - dgu * x);
    float gvy = gr * y + inv_r * (guy - dgu * y);
    float gvz = gr * z + inv_r * (guz - dgu * z);
    atomicAdd(&forces[snd * 3 + 0], gvx);
    atomicAdd(&forces[snd * 3 + 1], gvy);
    atomicAdd(&forces[snd * 3 + 2], gvz);
    atomicAdd(&forces[rcv * 3 + 0], -gvx);
    atomicAdd(&forces[rcv * 3 + 1], -gvy);
    atomicAdd(&forces[rcv * 3 + 2], -gvz);
}

// -------------------- node update / backward-prep --------------------

__global__ __launch_bounds__(256) void node_update(const float* __restrict__ agg,
                                                   const float* __restrict__ attrs,
                                                   const float* __restrict__ Wout,
                                                   const float* __restrict__ Wskip,
                                                   const float* __restrict__ wread,
                                                   const int* __restrict__ batch,
                                                   float* __restrict__ h_out,  // nullable
                                                   float* __restrict__ energy) {
    __shared__ float sa[2][FF];
    __shared__ float red[4];
    int sub = threadIdx.x >> 7;
    int f = threadIdx.x & 127;
    int n = blockIdx.x * 2 + sub;
    sa[sub][f] = agg[n * FF + f];
    __syncthreads();
    float acc = 0.f;
#pragma unroll 8
    for (int k = 0; k < FF; k++) acc += sa[sub][k] * Wout[k * FF + f];
#pragma unroll
    for (int a = 0; a < 10; a++) acc += attrs[n * 10 + a] * Wskip[a * FF + f];
    if (h_out) h_out[n * FF + f] = acc;
    float p = acc * wread[f];
#pragma unroll
    for (int o = 32; o > 0; o >>= 1) p += __shfl_xor(p, o);
    int wid = threadIdx.x >> 6;
    if ((threadIdx.x & 63) == 0) red[wid] = p;
    __syncthreads();
    if (f == 0) atomicAdd(&energy[batch[n]], red[2 * sub] + red[2 * sub + 1]);
}

__global__ __launch_bounds__(128) void a1_kernel(const float* __restrict__ Wout1,
                                                 const float* __restrict__ wread1,
                                                 float* __restrict__ a1) {
    int f = threadIdx.x;
    float s = 0.f;
    for (int k = 0; k < FF; k++) s += Wout1[f * FF + k] * wread1[k];
    a1[f] = s;
}

__global__ __launch_bounds__(256) void transpose_kernel(const float* __restrict__ Wout0,
                                                        float* __restrict__ WoT) {
    int idx = blockIdx.x * 256 + threadIdx.x;
    int f = idx & 127;
    int k = idx >> 7;
    WoT[k * FF + f] = Wout0[f * FF + k];
}

__global__ __launch_bounds__(256) void gh_init_kernel(const float* __restrict__ wread0,
                                                      float* __restrict__ gh) {
    int idx = blockIdx.x * 256 + threadIdx.x;
    gh[idx] = wread0[idx & 127];
}

__global__ __launch_bounds__(256) void node_b0(const float* __restrict__ gh,
                                               const float* __restrict__ WoT,
                                               float* __restrict__ b0out) {
    __shared__ float sa[2][FF];
    int sub = threadIdx.x >> 7;
    int f = threadIdx.x & 127;
    int n = blockIdx.x * 2 + sub;
    sa[sub][f] = gh[n * FF + f];
    __syncthreads();
    float acc = 0.f;
#pragma unroll 8
    for (int k = 0; k < FF; k++) acc += sa[sub][k] * WoT[k * FF + f];
    b0out[n * FF + f] = acc;
}

// -------------------- launch --------------------

extern "C" void kernel_launch(void* const* d_in, const int* in_sizes, int n_in,
                              void* d_out, int out_size, void* d_ws, size_t ws_size,
                              hipStream_t stream) {
    const float* pos    = (const float*)d_in[0];
    const float* attrs  = (const float*)d_in[1];
    const float* shifts = (const float*)d_in[2];
    const int*   ei     = (const int*)d_in[3];
    const int*   batch  = (const int*)d_in[4];
    const float* W_emb  = (const float*)d_in[6];
    const float* ae     = (const float*)d_in[7];
    const float* W_r    = (const float*)d_in[8];   // (2,8,F)
    const float* w_sh   = (const float*)d_in[9];   // (2,16)
    const float* W_out  = (const float*)d_in[10];  // (2,F,F)
    const float* W_skip = (const float*)d_in[11];  // (2,10,F)
    const float* w_read = (const float*)d_in[12];  // (2,F)

    float* energy = (float*)d_out;
    float* forces = energy + GG;

    float* ws  = (float*)d_ws;
    float* h0  = ws;                     // N*F
    float* h1  = h0 + (size_t)NN * FF;   // N*F
    float* agg = h1 + (size_t)NN * FF;   // N*F (reused as b0)
    float* gh  = agg + (size_t)NN * FF;  // N*F
    float* geo = gh + (size_t)NN * FF;   // 22*EE
    float* a1  = geo + (size_t)22 * EE;  // F
    float* WoT = a1 + FF;                // F*F

    const int FEAT_BLOCKS = 2048;        // grid-stride, 4 waves/block
    const int geomBlocks = (EE + 255) / 256;
    const int nodeBlocks = NN / 2;

    hipMemsetAsync(d_out, 0, (size_t)out_size * sizeof(float), stream);
    hipMemsetAsync(agg, 0, (size_t)NN * FF * sizeof(float), stream);

    e0_kernel<<<(NN + 255) / 256, 256, 0, stream>>>(attrs, ae, batch, energy);
    h0_kernel<<<nodeBlocks, 256, 0, stream>>>(attrs, W_emb, h0);
    edge_geom<<<geomBlocks, 256, 0, stream>>>(pos, shifts, ei, w_sh, geo);

    // layer 0 forward
    edge_fwd_feat<<<FEAT_BLOCKS, 256, 0, stream>>>(geo, geo + G_S0, ei, h0, W_r, agg);
    node_update<<<nodeBlocks, 256, 0, stream>>>(agg, attrs, W_out, W_skip, w_read, batch,
                                                h1, energy);

    // layer 1 forward
    hipMemsetAsync(agg, 0, (size_t)NN * FF * sizeof(float), stream);
    edge_fwd_feat<<<FEAT_BLOCKS, 256, 0, stream>>>(geo, geo + G_S1, ei, h1,
                                                   W_r + NBES * FF, agg);
    node_update<<<nodeBlocks, 256, 0, stream>>>(agg, attrs, W_out + FF * FF, W_skip + 10 * FF,
                                                w_read + FF, batch, nullptr, energy);

    // backward prep
    a1_kernel<<<1, 128, 0, stream>>>(W_out + FF * FF, w_read + FF, a1);
    transpose_kernel<<<FF * FF / 256, 256, 0, stream>>>(W_out, WoT);
    gh_init_kernel<<<NN * FF / 256, 256, 0, stream>>>(w_read, gh);

    // layer 1 backward: dsp1/drp1 + gh accumulation
    edge_bwd_feat<true><<<FEAT_BLOCKS, 256, 0, stream>>>(geo, geo + G_S1, ei, h1,
                                                         W_r + NBES * FF, a1, nullptr, gh,
                                                         geo + G_DSP1, geo + G_DRP1);
    // b0 = g1 @ W_out0^T (into agg buffer)
    node_b0<<<nodeBlocks, 256, 0, stream>>>(gh, WoT, agg);

    // layer 0 backward: dsp0/drp0
    edge_bwd_feat<false><<<FEAT_BLOCKS, 256, 0, stream>>>(geo, geo + G_S0, ei, h0,
                                                          W_r, nullptr, agg, nullptr,
                                                          geo + G_DSP0, geo + G_DRP0);

    // forces for both layers in one pass
    force_kernel<<<geomBlocks, 256, 0, stream>>>(pos, shifts, ei, w_sh, geo, forces);
}